// Round 5
// baseline (750.291 us; speedup 1.0000x reference)
//
#include <hip/hip_runtime.h>
#include <hip/hip_bf16.h>

#define B_ 8
#define C_ 256
#define N_ 4096
#define D_ 64

typedef __attribute__((ext_vector_type(8))) short bf16x8;
typedef __attribute__((ext_vector_type(4))) float f32x4;

__device__ __forceinline__ float bf2f(unsigned short h){
    return __uint_as_float(((unsigned int)h) << 16);
}
__device__ __forceinline__ unsigned short f2bf(float f){
    unsigned int u = __float_as_uint(f);
    u += 0x7FFFu + ((u >> 16) & 1u);
    return (unsigned short)(u >> 16);
}
__device__ __forceinline__ bf16x8 ldf(const unsigned short* p){
    return *(const bf16x8*)p;
}
__device__ __forceinline__ f32x4 mfma_bf16(bf16x8 a, bf16x8 b, f32x4 c){
    return __builtin_amdgcn_mfma_f32_16x16x32_bf16(a, b, c, 0, 0, 0);
}

// ---------------------------------------------------------------------------
// x [B,C,N] fp32 -> xhT/xlT [B,N,C] bf16 hi/lo
__global__ __launch_bounds__(256) void convert_x_kernel(
    const float* __restrict__ x,
    unsigned short* __restrict__ xhT, unsigned short* __restrict__ xlT)
{
    __shared__ float tile[64][65];
    int b = blockIdx.z, c0 = blockIdx.y * 64, n0 = blockIdx.x * 64;
    int tid = threadIdx.x;
    int cc = tid & 63, rb = tid >> 6;
    #pragma unroll
    for (int j = 0; j < 16; j++){
        int rr = rb + 4*j;
        tile[rr][cc] = x[((size_t)(b*C_ + c0 + rr))*N_ + n0 + cc];
    }
    __syncthreads();
    #pragma unroll
    for (int j = 0; j < 16; j++){
        int rr = rb + 4*j;
        float v = tile[cc][rr];
        unsigned short h = f2bf(v);
        unsigned short l = f2bf(v - bf2f(h));
        size_t o = ((size_t)(b*N_ + n0 + rr))*C_ + c0 + cc;
        xhT[o] = h; xlT[o] = l;
    }
}

__global__ __launch_bounds__(256) void convert_w_kernel(
    const float* __restrict__ Wqk, const float* __restrict__ Wv, const float* __restrict__ Wt,
    unsigned short* __restrict__ Wqk_hi, unsigned short* __restrict__ Wqk_lo,
    unsigned short* __restrict__ Wv_b, unsigned short* __restrict__ Wt_b)
{
    int i = blockIdx.x * 256 + threadIdx.x;
    if (i < D_*C_){
        float v = Wqk[i];
        unsigned short h = f2bf(v);
        Wqk_hi[i] = h; Wqk_lo[i] = f2bf(v - bf2f(h));
    }
    int j = i - D_*C_;
    if (j >= 0 && j < C_*C_) Wv_b[j] = f2bf(Wv[j]);
    int k = j - C_*C_;
    if (k >= 0 && k < C_*C_) Wt_b[k] = f2bf(Wt[k]);
}

// qk[b,n,d]: split-bf16 3-term. Out [B,N,64] hi/lo
__global__ __launch_bounds__(256) void proj_qk_kernel(
    const unsigned short* __restrict__ xhT, const unsigned short* __restrict__ xlT,
    const unsigned short* __restrict__ Wh,  const unsigned short* __restrict__ Wl,
    unsigned short* __restrict__ qh, unsigned short* __restrict__ ql)
{
    int b = blockIdx.z, n0 = blockIdx.x * 64;
    int tid = threadIdx.x, w = tid >> 6, lane = tid & 63, q = lane >> 4, r = lane & 15;
    f32x4 z = {0.f,0.f,0.f,0.f};
    f32x4 acc[4] = {z,z,z,z};
    const unsigned short* Ah = Wh + (size_t)(16*w + r)*C_;
    const unsigned short* Al = Wl + (size_t)(16*w + r)*C_;
    const unsigned short* Bh = xhT + ((size_t)(b*N_ + n0 + r))*C_;
    const unsigned short* Bl = xlT + ((size_t)(b*N_ + n0 + r))*C_;
    for (int k0 = 0; k0 < C_; k0 += 32){
        bf16x8 ah = ldf(Ah + k0 + 8*q);
        bf16x8 al = ldf(Al + k0 + 8*q);
        #pragma unroll
        for (int f = 0; f < 4; f++){
            bf16x8 bh = ldf(Bh + (size_t)(16*f)*C_ + k0 + 8*q);
            bf16x8 bl = ldf(Bl + (size_t)(16*f)*C_ + k0 + 8*q);
            acc[f] = mfma_bf16(ah, bh, acc[f]);
            acc[f] = mfma_bf16(ah, bl, acc[f]);
            acc[f] = mfma_bf16(al, bh, acc[f]);
        }
    }
    #pragma unroll
    for (int f = 0; f < 4; f++){
        int col = n0 + 16*f + r;
        int d0 = 16*w + 4*q;
        size_t o = ((size_t)(b*N_ + col))*D_ + d0;
        ushort4 hv, lv;
        float v0 = acc[f][0], v1 = acc[f][1], v2 = acc[f][2], v3 = acc[f][3];
        hv.x = f2bf(v0); lv.x = f2bf(v0 - bf2f(hv.x));
        hv.y = f2bf(v1); lv.y = f2bf(v1 - bf2f(hv.y));
        hv.z = f2bf(v2); lv.z = f2bf(v2 - bf2f(hv.z));
        hv.w = f2bf(v3); lv.w = f2bf(v3 - bf2f(hv.w));
        *(ushort4*)(qh + o) = hv;
        *(ushort4*)(ql + o) = lv;
    }
}

// nrm[b,n] = ||q_n||  (wave per row)
__global__ __launch_bounds__(256) void qnorm_kernel(
    const unsigned short* __restrict__ qh, const unsigned short* __restrict__ ql,
    float* __restrict__ nrm)
{
    int rowg = blockIdx.x * 4 + (threadIdx.x >> 6);
    int lane = threadIdx.x & 63;
    float v = bf2f(qh[(size_t)rowg*D_ + lane]) + bf2f(ql[(size_t)rowg*D_ + lane]);
    float p = v*v;
    #pragma unroll
    for (int o = 1; o < 64; o <<= 1) p += __shfl_xor(p, o);
    if (lane == 0) nrm[rowg] = sqrtf(p);
}

// M[b] = max_n nrm[b,n]
__global__ __launch_bounds__(256) void qmax_kernel(
    const float* __restrict__ nrm, float* __restrict__ Mv)
{
    __shared__ float red[4];
    int b = blockIdx.x, tid = threadIdx.x, w = tid >> 6, lane = tid & 63;
    float m = 0.f;
    for (int i = tid; i < N_; i += 256) m = fmaxf(m, nrm[(size_t)b*N_ + i]);
    #pragma unroll
    for (int o = 1; o < 64; o <<= 1) m = fmaxf(m, __shfl_xor(m, o));
    if (lane == 0) red[w] = m;
    __syncthreads();
    if (tid == 0) Mv[b] = fmaxf(fmaxf(red[0], red[1]), fmaxf(red[2], red[3]));
}

// x_v[b,d,n] = Wv x + bv -> xvb [B,C,N] bf16
__global__ __launch_bounds__(256) void proj_v_kernel(
    const unsigned short* __restrict__ xhT, const unsigned short* __restrict__ Wvb,
    const float* __restrict__ bv, unsigned short* __restrict__ xvb)
{
    int b = blockIdx.z, n0 = blockIdx.x * 64, d0 = blockIdx.y * 64;
    int tid = threadIdx.x, w = tid >> 6, lane = tid & 63, q = lane >> 4, r = lane & 15;
    f32x4 z = {0.f,0.f,0.f,0.f};
    f32x4 acc[4] = {z,z,z,z};
    const unsigned short* A = Wvb + (size_t)(d0 + 16*w + r)*C_;
    const unsigned short* Bb = xhT + ((size_t)(b*N_ + n0 + r))*C_;
    for (int k0 = 0; k0 < C_; k0 += 32){
        bf16x8 a = ldf(A + k0 + 8*q);
        #pragma unroll
        for (int f = 0; f < 4; f++){
            bf16x8 bb = ldf(Bb + (size_t)(16*f)*C_ + k0 + 8*q);
            acc[f] = mfma_bf16(a, bb, acc[f]);
        }
    }
    #pragma unroll
    for (int f = 0; f < 4; f++){
        int col = n0 + 16*f + r;
        #pragma unroll
        for (int i = 0; i < 4; i++){
            int row = d0 + 16*w + 4*q + i;
            float v = acc[f][i] + bv[row];
            xvb[((size_t)(b*C_ + row))*N_ + col] = f2bf(v);
        }
    }
}

// ---------------------------------------------------------------------------
// Pass 1 (m-split x4 for occupancy): partial rowsum of exp(e - nrm_n*M).
// Grid (N/64, 4, B) = 2048 blocks -> 8 blocks/CU, VGPR ~36 -> full wave slots.
__global__ __launch_bounds__(256) void rsum_kernel(
    const unsigned short* __restrict__ qh, const unsigned short* __restrict__ ql,
    const float* __restrict__ nrm, const float* __restrict__ Mv,
    float* __restrict__ rsum_part)
{
    int n0 = blockIdx.x * 64, ms = blockIdx.y, b = blockIdx.z;
    int tid = threadIdx.x, w = tid >> 6, lane = tid & 63, q = lane >> 4, r = lane & 15;
    const unsigned short* qb = qh + (size_t)b*N_*D_;
    const unsigned short* lb = ql + (size_t)b*N_*D_;
    const unsigned short* ap  = qb + (size_t)(n0 + 16*w + r)*D_ + 8*q;
    const unsigned short* alp = lb + (size_t)(n0 + 16*w + r)*D_ + 8*q;
    bf16x8 Ah0 = ldf(ap), Ah1 = ldf(ap+32), Al0 = ldf(alp), Al1 = ldf(alp+32);
    float M = Mv[b];
    float4 nv = *(const float4*)&nrm[(size_t)b*N_ + n0 + 16*w + 4*q];
    float sh[4] = {nv.x*M, nv.y*M, nv.z*M, nv.w*M};
    float rs[4] = {0.f,0.f,0.f,0.f};
    for (int mt = 0; mt < 16; mt++){
        int m0 = ms*1024 + mt*64;
        f32x4 z = {0.f,0.f,0.f,0.f};
        f32x4 e[4] = {z,z,z,z};
        #pragma unroll
        for (int f = 0; f < 4; f++){
            const unsigned short* bp  = qb + (size_t)(m0 + 16*f + r)*D_ + 8*q;
            const unsigned short* blp = lb + (size_t)(m0 + 16*f + r)*D_ + 8*q;
            bf16x8 bh0 = ldf(bp), bh1 = ldf(bp+32);
            bf16x8 bl0 = ldf(blp), bl1 = ldf(blp+32);
            e[f] = mfma_bf16(Ah0, bh0, e[f]);
            e[f] = mfma_bf16(Ah0, bl0, e[f]);
            e[f] = mfma_bf16(Al0, bh0, e[f]);
            e[f] = mfma_bf16(Ah1, bh1, e[f]);
            e[f] = mfma_bf16(Ah1, bl1, e[f]);
            e[f] = mfma_bf16(Al1, bh1, e[f]);
        }
        #pragma unroll
        for (int i = 0; i < 4; i++){
            rs[i] += __expf(e[0][i] - sh[i]) + __expf(e[1][i] - sh[i])
                   + __expf(e[2][i] - sh[i]) + __expf(e[3][i] - sh[i]);
        }
    }
    #pragma unroll
    for (int i = 0; i < 4; i++){
        #pragma unroll
        for (int o = 1; o < 16; o <<= 1) rs[i] += __shfl_xor(rs[i], o);
    }
    if (r == 0){
        float4 v; v.x = rs[0]; v.y = rs[1]; v.z = rs[2]; v.w = rs[3];
        *(float4*)&rsum_part[((size_t)ms*B_ + b)*N_ + n0 + 16*w + 4*q] = v;
    }
}

// shift2[b,n] = nrm*M + log(sum of 4 partials)
__global__ __launch_bounds__(256) void shiftfin_kernel(
    const float* __restrict__ rsum_part, const float* __restrict__ nrm,
    const float* __restrict__ Mv, float* __restrict__ shift2)
{
    int gi = blockIdx.x * 256 + threadIdx.x;   // over B*N
    int b = gi >> 12;
    float s = rsum_part[gi] + rsum_part[(size_t)B_*N_ + gi]
            + rsum_part[(size_t)2*B_*N_ + gi] + rsum_part[(size_t)3*B_*N_ + gi];
    shift2[gi] = nrm[gi]*Mv[b] + __logf(s);
}

// ---------------------------------------------------------------------------
// Pass 2: fused attention+PV, software-pipelined:
//  - P~ LDS tile double-buffered (ONE barrier per n-tile)
//  - next A-frags + this iter's xv frags issued before the barrier
__global__ __launch_bounds__(256, 2) void pv_kernel(
    const unsigned short* __restrict__ qh, const unsigned short* __restrict__ ql,
    const unsigned short* __restrict__ xvb, const float* __restrict__ shift2,
    const float* __restrict__ x, unsigned short* __restrict__ uT)
{
    __shared__ unsigned short Pt[2][64*72];   // P~ tile [m][n], stride 72
    __shared__ float red[4][64];
    __shared__ float csinv[64];
    int b = blockIdx.x, m0 = blockIdx.y * 64;
    int tid = threadIdx.x, w = tid >> 6, lane = tid & 63, q = lane >> 4, r = lane & 15;
    const unsigned short* qb = qh + (size_t)b*N_*D_;
    const unsigned short* lb = ql + (size_t)b*N_*D_;
    // persistent B-frags: q rows m0..m0+63 (hi+lo)
    bf16x8 Bh[4][2], Bl[4][2];
    #pragma unroll
    for (int f = 0; f < 4; f++){
        const unsigned short* bp  = qb + (size_t)(m0 + 16*f + r)*D_ + 8*q;
        const unsigned short* blp = lb + (size_t)(m0 + 16*f + r)*D_ + 8*q;
        Bh[f][0] = ldf(bp);  Bh[f][1] = ldf(bp+32);
        Bl[f][0] = ldf(blp); Bl[f][1] = ldf(blp+32);
    }
    const unsigned short* xvbase = xvb + (size_t)b*C_*N_;
    f32x4 z = {0.f,0.f,0.f,0.f};
    f32x4 accv[4][4];      // [cf][fm]: c = 64w+16cf+4q+i, m = m0+16fm+r
    #pragma unroll
    for (int cf = 0; cf < 4; cf++)
        #pragma unroll
        for (int fm = 0; fm < 4; fm++) accv[cf][fm] = z;
    float cs[4] = {0.f,0.f,0.f,0.f};

    // prologue: A-frags for ns=0
    const unsigned short* ap0  = qb + (size_t)(16*w + r)*D_ + 8*q;
    const unsigned short* alp0 = lb + (size_t)(16*w + r)*D_ + 8*q;
    bf16x8 Ah0 = ldf(ap0), Ah1 = ldf(ap0+32), Al0 = ldf(alp0), Al1 = ldf(alp0+32);
    int buf = 0;

    for (int ns = 0; ns < N_; ns += 64){
        // xv frags for this iter (issued early; consumed after the barrier)
        bf16x8 xvf[2][4];
        #pragma unroll
        for (int kc = 0; kc < 2; kc++)
            #pragma unroll
            for (int cf = 0; cf < 4; cf++)
                xvf[kc][cf] = ldf(xvbase + (size_t)(64*w + 16*cf + r)*N_ + ns + kc*32 + 8*q);
        // ---- energy tile (A-frags already in regs)
        f32x4 e[4] = {z,z,z,z};
        #pragma unroll
        for (int f = 0; f < 4; f++){
            e[f] = mfma_bf16(Ah0, Bh[f][0], e[f]);
            e[f] = mfma_bf16(Ah0, Bl[f][0], e[f]);
            e[f] = mfma_bf16(Al0, Bh[f][0], e[f]);
            e[f] = mfma_bf16(Ah1, Bh[f][1], e[f]);
            e[f] = mfma_bf16(Ah1, Bl[f][1], e[f]);
            e[f] = mfma_bf16(Al1, Bh[f][1], e[f]);
        }
        // ---- prefetch next A-frags (WAR-safe: energy MFMAs already issued)
        if (ns + 64 < N_){
            const unsigned short* ap  = qb + (size_t)(ns + 64 + 16*w + r)*D_ + 8*q;
            const unsigned short* alp = lb + (size_t)(ns + 64 + 16*w + r)*D_ + 8*q;
            Ah0 = ldf(ap); Ah1 = ldf(ap+32); Al0 = ldf(alp); Al1 = ldf(alp+32);
        }
        // ---- exp + store P~ into current buffer
        float4 s2 = *(const float4*)&shift2[(size_t)b*N_ + ns + 16*w + 4*q];
        float sh[4] = {s2.x, s2.y, s2.z, s2.w};
        #pragma unroll
        for (int f = 0; f < 4; f++){
            float p0 = __expf(e[f][0] - sh[0]);
            float p1 = __expf(e[f][1] - sh[1]);
            float p2 = __expf(e[f][2] - sh[2]);
            float p3 = __expf(e[f][3] - sh[3]);
            cs[f] += p0 + p1 + p2 + p3;
            ushort4 pv4;
            pv4.x = f2bf(p0); pv4.y = f2bf(p1); pv4.z = f2bf(p2); pv4.w = f2bf(p3);
            *(ushort4*)&Pt[buf][(16*f + r)*72 + 16*w + 4*q] = pv4;
        }
        __syncthreads();
        // ---- PV MFMAs from current buffer (writes of next iter go to buf^1)
        #pragma unroll
        for (int kc = 0; kc < 2; kc++){
            bf16x8 bfr[4];
            #pragma unroll
            for (int fm = 0; fm < 4; fm++)
                bfr[fm] = *(bf16x8*)&Pt[buf][(16*fm + r)*72 + kc*32 + 8*q];
            #pragma unroll
            for (int cf = 0; cf < 4; cf++)
                #pragma unroll
                for (int fm = 0; fm < 4; fm++)
                    accv[cf][fm] = mfma_bf16(xvf[kc][cf], bfr[fm], accv[cf][fm]);
        }
        buf ^= 1;
    }
    // ---- colsum reduce
    #pragma unroll
    for (int f = 0; f < 4; f++){
        float v = cs[f];
        v += __shfl_xor(v, 16);
        v += __shfl_xor(v, 32);
        if (q == 0) red[w][16*f + r] = v;
    }
    __syncthreads();
    if (tid < 64)
        csinv[tid] = 1.0f / (1e-9f + red[0][tid] + red[1][tid] + red[2][tid] + red[3][tid]);
    __syncthreads();
    // ---- epilogue
    #pragma unroll
    for (int fm = 0; fm < 4; fm++){
        int m = m0 + 16*fm + r;
        float inv = csinv[16*fm + r];
        #pragma unroll
        for (int cf = 0; cf < 4; cf++){
            int c0r = 64*w + 16*cf + 4*q;
            float u0 = x[(size_t)(b*C_ + c0r+0)*N_ + m] - accv[cf][fm][0]*inv;
            float u1 = x[(size_t)(b*C_ + c0r+1)*N_ + m] - accv[cf][fm][1]*inv;
            float u2 = x[(size_t)(b*C_ + c0r+2)*N_ + m] - accv[cf][fm][2]*inv;
            float u3 = x[(size_t)(b*C_ + c0r+3)*N_ + m] - accv[cf][fm][3]*inv;
            ushort4 uv;
            uv.x = f2bf(u0); uv.y = f2bf(u1); uv.z = f2bf(u2); uv.w = f2bf(u3);
            *(ushort4*)&uT[((size_t)b*N_ + m)*C_ + c0r] = uv;
        }
    }
}

// ---------------------------------------------------------------------------
__global__ __launch_bounds__(256) void t_stats_kernel(
    const unsigned short* __restrict__ uT, const unsigned short* __restrict__ Wtb,
    float* __restrict__ bnsum, float* __restrict__ bnsq)
{
    int b = blockIdx.z, n0 = blockIdx.x * 64, d0 = blockIdx.y * 64;
    int tid = threadIdx.x, w = tid >> 6, lane = tid & 63, q = lane >> 4, r = lane & 15;
    f32x4 z = {0.f,0.f,0.f,0.f};
    f32x4 acc[4] = {z,z,z,z};
    const unsigned short* A = Wtb + (size_t)(d0 + 16*w + r)*C_;
    const unsigned short* Bb = uT + ((size_t)(b*N_ + n0 + r))*C_;
    for (int k0 = 0; k0 < C_; k0 += 32){
        bf16x8 a = ldf(A + k0 + 8*q);
        #pragma unroll
        for (int f = 0; f < 4; f++){
            bf16x8 bb = ldf(Bb + (size_t)(16*f)*C_ + k0 + 8*q);
            acc[f] = mfma_bf16(a, bb, acc[f]);
        }
    }
    #pragma unroll
    for (int i = 0; i < 4; i++){
        float s = 0.f, s2 = 0.f;
        #pragma unroll
        for (int f = 0; f < 4; f++){ float v = acc[f][i]; s += v; s2 += v*v; }
        #pragma unroll
        for (int o = 1; o < 16; o <<= 1){ s += __shfl_xor(s, o); s2 += __shfl_xor(s2, o); }
        if (r == 0){
            int d = d0 + 16*w + 4*q + i;
            atomicAdd(&bnsum[d], s);
            atomicAdd(&bnsq[d], s2);
        }
    }
}

__global__ __launch_bounds__(256) void bn_final_kernel(
    const float* __restrict__ bnsum, const float* __restrict__ bnsq,
    const float* __restrict__ gamma, const float* __restrict__ beta,
    float* __restrict__ scale, float* __restrict__ shift)
{
    int d = threadIdx.x;
    const float inv = 1.0f / (B_ * N_);
    float m = bnsum[d] * inv;
    float v = bnsq[d] * inv - m*m;
    float rs = rsqrtf(v + 1e-5f);
    float sc = gamma[d] * rs;
    scale[d] = sc;
    shift[d] = beta[d] - m*sc;
}

__global__ __launch_bounds__(256) void final_kernel(
    const unsigned short* __restrict__ uT, const unsigned short* __restrict__ Wtb,
    const float* __restrict__ scale, const float* __restrict__ shift,
    const float* __restrict__ x, float* __restrict__ out)
{
    int b = blockIdx.z, n0 = blockIdx.x * 64, d0 = blockIdx.y * 64;
    int tid = threadIdx.x, w = tid >> 6, lane = tid & 63, q = lane >> 4, r = lane & 15;
    f32x4 z = {0.f,0.f,0.f,0.f};
    f32x4 acc[4] = {z,z,z,z};
    const unsigned short* A = Wtb + (size_t)(d0 + 16*w + r)*C_;
    const unsigned short* Bb = uT + ((size_t)(b*N_ + n0 + r))*C_;
    for (int k0 = 0; k0 < C_; k0 += 32){
        bf16x8 a = ldf(A + k0 + 8*q);
        #pragma unroll
        for (int f = 0; f < 4; f++){
            bf16x8 bb = ldf(Bb + (size_t)(16*f)*C_ + k0 + 8*q);
            acc[f] = mfma_bf16(a, bb, acc[f]);
        }
    }
    #pragma unroll
    for (int f = 0; f < 4; f++){
        int n = n0 + 16*f + r;
        #pragma unroll
        for (int i = 0; i < 4; i++){
            int d = d0 + 16*w + 4*q + i;
            float tv = acc[f][i]*scale[d] + shift[d];
            tv = fmaxf(tv, 0.0f);
            size_t o = ((size_t)(b*C_ + d))*N_ + n;
            out[o] = x[o] + tv;
        }
    }
}

// ---------------------------------------------------------------------------
extern "C" void kernel_launch(void* const* d_in, const int* in_sizes, int n_in,
                              void* d_out, int out_size, void* d_ws, size_t ws_size,
                              hipStream_t stream)
{
    const float* x     = (const float*)d_in[0];
    const float* Wqk   = (const float*)d_in[1];
    const float* Wv    = (const float*)d_in[2];
    const float* bv    = (const float*)d_in[3];
    const float* Wt    = (const float*)d_in[4];
    // d_in[5] = bt : cancels exactly through training-mode BatchNorm
    const float* gamma = (const float*)d_in[6];
    const float* beta  = (const float*)d_in[7];
    float* out = (float*)d_out;

    char* ws = (char*)d_ws;
    size_t off = 0;
    auto alloc = [&](size_t bytes) -> void* {
        void* p = ws + off;
        off += (bytes + 255) & ~(size_t)255;
        return p;
    };
    unsigned short* xhT    = (unsigned short*)alloc((size_t)B_*N_*C_*2);
    unsigned short* xlT    = (unsigned short*)alloc((size_t)B_*N_*C_*2);
    unsigned short* Wqk_hi = (unsigned short*)alloc((size_t)D_*C_*2);
    unsigned short* Wqk_lo = (unsigned short*)alloc((size_t)D_*C_*2);
    unsigned short* Wv_b   = (unsigned short*)alloc((size_t)C_*C_*2);
    unsigned short* Wt_b   = (unsigned short*)alloc((size_t)C_*C_*2);
    unsigned short* qh     = (unsigned short*)alloc((size_t)B_*N_*D_*2);
    unsigned short* ql     = (unsigned short*)alloc((size_t)B_*N_*D_*2);
    unsigned short* xvb    = (unsigned short*)alloc((size_t)B_*C_*N_*2);
    unsigned short* uT     = (unsigned short*)alloc((size_t)B_*N_*C_*2);
    float*          nrm    = (float*)alloc((size_t)B_*N_*4);
    float*          Mv     = (float*)alloc(B_*4);
    float*          rsum_part = (float*)alloc((size_t)4*B_*N_*4);
    float*          shift2 = (float*)alloc((size_t)B_*N_*4);
    float*          bnsum  = (float*)alloc(256*4);
    float*          bnsq   = (float*)alloc(256*4);
    float*          scale  = (float*)alloc(256*4);
    float*          shiftb = (float*)alloc(256*4);

    convert_x_kernel<<<dim3(N_/64, C_/64, B_), 256, 0, stream>>>(x, xhT, xlT);
    convert_w_kernel<<<(D_*C_ + 2*C_*C_ + 255)/256, 256, 0, stream>>>(
        Wqk, Wv, Wt, Wqk_hi, Wqk_lo, Wv_b, Wt_b);
    proj_qk_kernel<<<dim3(N_/64, 1, B_), 256, 0, stream>>>(xhT, xlT, Wqk_hi, Wqk_lo, qh, ql);
    qnorm_kernel<<<(B_*N_)/4, 256, 0, stream>>>(qh, ql, nrm);
    qmax_kernel<<<B_, 256, 0, stream>>>(nrm, Mv);
    proj_v_kernel<<<dim3(N_/64, C_/64, B_), 256, 0, stream>>>(xhT, Wv_b, bv, xvb);

    rsum_kernel<<<dim3(N_/64, 4, B_), 256, 0, stream>>>(qh, ql, nrm, Mv, rsum_part);
    shiftfin_kernel<<<(B_*N_)/256, 256, 0, stream>>>(rsum_part, nrm, Mv, shift2);
    pv_kernel<<<dim3(B_, N_/64), 256, 0, stream>>>(qh, ql, xvb, shift2, x, uT);

    hipMemsetAsync(bnsum, 0, 256*4, stream);
    hipMemsetAsync(bnsq, 0, 256*4, stream);
    t_stats_kernel<<<dim3(N_/64, C_/64, B_), 256, 0, stream>>>(uT, Wt_b, bnsum, bnsq);
    bn_final_kernel<<<1, 256, 0, stream>>>(bnsum, bnsq, gamma, beta, scale, shiftb);
    final_kernel<<<dim3(N_/64, C_/64, B_), 256, 0, stream>>>(uT, Wt_b, scale, shiftb, x, out);
}

// Round 6
// 509.362 us; speedup vs baseline: 1.4730x; 1.4730x over previous
//
#include <hip/hip_runtime.h>
#include <hip/hip_bf16.h>

#define B_ 8
#define C_ 256
#define N_ 4096
#define D_ 64

typedef __attribute__((ext_vector_type(8))) short bf16x8;
typedef __attribute__((ext_vector_type(4))) float f32x4;

__device__ __forceinline__ float bf2f(unsigned short h){
    return __uint_as_float(((unsigned int)h) << 16);
}
__device__ __forceinline__ unsigned short f2bf(float f){
    unsigned int u = __float_as_uint(f);
    u += 0x7FFFu + ((u >> 16) & 1u);
    return (unsigned short)(u >> 16);
}
__device__ __forceinline__ bf16x8 ldf(const unsigned short* p){
    return *(const bf16x8*)p;
}
__device__ __forceinline__ f32x4 mfma_bf16(bf16x8 a, bf16x8 b, f32x4 c){
    return __builtin_amdgcn_mfma_f32_16x16x32_bf16(a, b, c, 0, 0, 0);
}
__device__ __forceinline__ void gld_lds16(const unsigned short* g, unsigned short* l){
    __builtin_amdgcn_global_load_lds(
        (const __attribute__((address_space(1))) unsigned int*)g,
        (__attribute__((address_space(3))) unsigned int*)l, 16, 0, 0);
}

// ---------------------------------------------------------------------------
// x [B,C,N] fp32 -> xhT/xlT [B,N,C] bf16 hi/lo
__global__ __launch_bounds__(256) void convert_x_kernel(
    const float* __restrict__ x,
    unsigned short* __restrict__ xhT, unsigned short* __restrict__ xlT)
{
    __shared__ float tile[64][65];
    int b = blockIdx.z, c0 = blockIdx.y * 64, n0 = blockIdx.x * 64;
    int tid = threadIdx.x;
    int cc = tid & 63, rb = tid >> 6;
    #pragma unroll
    for (int j = 0; j < 16; j++){
        int rr = rb + 4*j;
        tile[rr][cc] = x[((size_t)(b*C_ + c0 + rr))*N_ + n0 + cc];
    }
    __syncthreads();
    #pragma unroll
    for (int j = 0; j < 16; j++){
        int rr = rb + 4*j;
        float v = tile[cc][rr];
        unsigned short h = f2bf(v);
        unsigned short l = f2bf(v - bf2f(h));
        size_t o = ((size_t)(b*N_ + n0 + rr))*C_ + c0 + cc;
        xhT[o] = h; xlT[o] = l;
    }
}

__global__ __launch_bounds__(256) void convert_w_kernel(
    const float* __restrict__ Wqk, const float* __restrict__ Wv, const float* __restrict__ Wt,
    unsigned short* __restrict__ Wqk_hi, unsigned short* __restrict__ Wqk_lo,
    unsigned short* __restrict__ Wv_b, unsigned short* __restrict__ Wt_b)
{
    int i = blockIdx.x * 256 + threadIdx.x;
    if (i < D_*C_){
        float v = Wqk[i];
        unsigned short h = f2bf(v);
        Wqk_hi[i] = h; Wqk_lo[i] = f2bf(v - bf2f(h));
    }
    int j = i - D_*C_;
    if (j >= 0 && j < C_*C_) Wv_b[j] = f2bf(Wv[j]);
    int k = j - C_*C_;
    if (k >= 0 && k < C_*C_) Wt_b[k] = f2bf(Wt[k]);
}

// qk[b,n,d]: split-bf16 3-term. Out [B,N,64] hi/lo
__global__ __launch_bounds__(256) void proj_qk_kernel(
    const unsigned short* __restrict__ xhT, const unsigned short* __restrict__ xlT,
    const unsigned short* __restrict__ Wh,  const unsigned short* __restrict__ Wl,
    unsigned short* __restrict__ qh, unsigned short* __restrict__ ql)
{
    int b = blockIdx.z, n0 = blockIdx.x * 64;
    int tid = threadIdx.x, w = tid >> 6, lane = tid & 63, q = lane >> 4, r = lane & 15;
    f32x4 z = {0.f,0.f,0.f,0.f};
    f32x4 acc[4] = {z,z,z,z};
    const unsigned short* Ah = Wh + (size_t)(16*w + r)*C_;
    const unsigned short* Al = Wl + (size_t)(16*w + r)*C_;
    const unsigned short* Bh = xhT + ((size_t)(b*N_ + n0 + r))*C_;
    const unsigned short* Bl = xlT + ((size_t)(b*N_ + n0 + r))*C_;
    for (int k0 = 0; k0 < C_; k0 += 32){
        bf16x8 ah = ldf(Ah + k0 + 8*q);
        bf16x8 al = ldf(Al + k0 + 8*q);
        #pragma unroll
        for (int f = 0; f < 4; f++){
            bf16x8 bh = ldf(Bh + (size_t)(16*f)*C_ + k0 + 8*q);
            bf16x8 bl = ldf(Bl + (size_t)(16*f)*C_ + k0 + 8*q);
            acc[f] = mfma_bf16(ah, bh, acc[f]);
            acc[f] = mfma_bf16(ah, bl, acc[f]);
            acc[f] = mfma_bf16(al, bh, acc[f]);
        }
    }
    #pragma unroll
    for (int f = 0; f < 4; f++){
        int col = n0 + 16*f + r;
        int d0 = 16*w + 4*q;
        size_t o = ((size_t)(b*N_ + col))*D_ + d0;
        ushort4 hv, lv;
        float v0 = acc[f][0], v1 = acc[f][1], v2 = acc[f][2], v3 = acc[f][3];
        hv.x = f2bf(v0); lv.x = f2bf(v0 - bf2f(hv.x));
        hv.y = f2bf(v1); lv.y = f2bf(v1 - bf2f(hv.y));
        hv.z = f2bf(v2); lv.z = f2bf(v2 - bf2f(hv.z));
        hv.w = f2bf(v3); lv.w = f2bf(v3 - bf2f(hv.w));
        *(ushort4*)(qh + o) = hv;
        *(ushort4*)(ql + o) = lv;
    }
}

// nrm[b,n] = ||q_n||  (wave per row)
__global__ __launch_bounds__(256) void qnorm_kernel(
    const unsigned short* __restrict__ qh, const unsigned short* __restrict__ ql,
    float* __restrict__ nrm)
{
    int rowg = blockIdx.x * 4 + (threadIdx.x >> 6);
    int lane = threadIdx.x & 63;
    float v = bf2f(qh[(size_t)rowg*D_ + lane]) + bf2f(ql[(size_t)rowg*D_ + lane]);
    float p = v*v;
    #pragma unroll
    for (int o = 1; o < 64; o <<= 1) p += __shfl_xor(p, o);
    if (lane == 0) nrm[rowg] = sqrtf(p);
}

// M[b] = max_n nrm[b,n]
__global__ __launch_bounds__(256) void qmax_kernel(
    const float* __restrict__ nrm, float* __restrict__ Mv)
{
    __shared__ float red[4];
    int b = blockIdx.x, tid = threadIdx.x, w = tid >> 6, lane = tid & 63;
    float m = 0.f;
    for (int i = tid; i < N_; i += 256) m = fmaxf(m, nrm[(size_t)b*N_ + i]);
    #pragma unroll
    for (int o = 1; o < 64; o <<= 1) m = fmaxf(m, __shfl_xor(m, o));
    if (lane == 0) red[w] = m;
    __syncthreads();
    if (tid == 0) Mv[b] = fmaxf(fmaxf(red[0], red[1]), fmaxf(red[2], red[3]));
}

// x_v[b,d,n] = Wv x + bv -> xvb [B,C,N] bf16
__global__ __launch_bounds__(256) void proj_v_kernel(
    const unsigned short* __restrict__ xhT, const unsigned short* __restrict__ Wvb,
    const float* __restrict__ bv, unsigned short* __restrict__ xvb)
{
    int b = blockIdx.z, n0 = blockIdx.x * 64, d0 = blockIdx.y * 64;
    int tid = threadIdx.x, w = tid >> 6, lane = tid & 63, q = lane >> 4, r = lane & 15;
    f32x4 z = {0.f,0.f,0.f,0.f};
    f32x4 acc[4] = {z,z,z,z};
    const unsigned short* A = Wvb + (size_t)(d0 + 16*w + r)*C_;
    const unsigned short* Bb = xhT + ((size_t)(b*N_ + n0 + r))*C_;
    for (int k0 = 0; k0 < C_; k0 += 32){
        bf16x8 a = ldf(A + k0 + 8*q);
        #pragma unroll
        for (int f = 0; f < 4; f++){
            bf16x8 bb = ldf(Bb + (size_t)(16*f)*C_ + k0 + 8*q);
            acc[f] = mfma_bf16(a, bb, acc[f]);
        }
    }
    #pragma unroll
    for (int f = 0; f < 4; f++){
        int col = n0 + 16*f + r;
        #pragma unroll
        for (int i = 0; i < 4; i++){
            int row = d0 + 16*w + 4*q + i;
            float v = acc[f][i] + bv[row];
            xvb[((size_t)(b*C_ + row))*N_ + col] = f2bf(v);
        }
    }
}

// ---------------------------------------------------------------------------
// Pass 1 v3: tiled GEMM. Block = 128 n-rows x 1024 m-sweep. A-frags (n-side,
// wave-private) in registers; B-tile (m-side, shared by 4 waves) staged into
// LDS via global_load_lds (XOR-chunk swizzle, conflict-free reads).
// Grid (B, N/128, 4): blockIdx.x = batch -> XCD pinning keeps q L2-resident.
__global__ __launch_bounds__(256) void rsum_kernel(
    const unsigned short* __restrict__ qh, const unsigned short* __restrict__ ql,
    const float* __restrict__ nrm, const float* __restrict__ Mv,
    float* __restrict__ rsum_part)
{
    __shared__ unsigned short Bh_lds[64*64];   // hi tile, 8 KB
    __shared__ unsigned short Bl_lds[64*64];   // lo tile, 8 KB
    int b = blockIdx.x, n0 = blockIdx.y * 128, ms = blockIdx.z;
    int tid = threadIdx.x, w = tid >> 6, lane = tid & 63, q = lane >> 4, r = lane & 15;
    int lrow = lane >> 3, lch = lane & 7;
    const unsigned short* qb = qh + (size_t)b*N_*D_;
    const unsigned short* lb = ql + (size_t)b*N_*D_;
    // A-frags: 2 n-groups per wave, loaded once
    bf16x8 Ah[2][2], Al[2][2];
    #pragma unroll
    for (int g = 0; g < 2; g++){
        int row = n0 + 32*w + 16*g + r;
        const unsigned short* ap  = qb + (size_t)row*D_ + 8*q;
        const unsigned short* alp = lb + (size_t)row*D_ + 8*q;
        Ah[g][0] = ldf(ap);  Ah[g][1] = ldf(ap+32);
        Al[g][0] = ldf(alp); Al[g][1] = ldf(alp+32);
    }
    float M = Mv[b];
    float sh[2][4], rs[2][4];
    #pragma unroll
    for (int g = 0; g < 2; g++){
        float4 nv = *(const float4*)&nrm[(size_t)b*N_ + n0 + 32*w + 16*g + 4*q];
        sh[g][0] = nv.x*M; sh[g][1] = nv.y*M; sh[g][2] = nv.z*M; sh[g][3] = nv.w*M;
        rs[g][0] = rs[g][1] = rs[g][2] = rs[g][3] = 0.f;
    }
    f32x4 z = {0.f,0.f,0.f,0.f};
    for (int mt = 0; mt < 16; mt++){
        int m0 = ms*1024 + mt*64;
        // stage B tile: 64 rows x 64 elems (hi & lo), XOR-chunk swizzle
        #pragma unroll
        for (int i = 0; i < 2; i++){
            int row = i*32 + w*8 + lrow;
            int sc = lch ^ (row & 7);
            gld_lds16(qb + (size_t)(m0 + row)*D_ + sc*8, &Bh_lds[(i*32 + w*8)*64]);
            gld_lds16(lb + (size_t)(m0 + row)*D_ + sc*8, &Bl_lds[(i*32 + w*8)*64]);
        }
        __syncthreads();
        f32x4 e[2][4];
        #pragma unroll
        for (int g = 0; g < 2; g++)
            #pragma unroll
            for (int f = 0; f < 4; f++) e[g][f] = z;
        #pragma unroll
        for (int f = 0; f < 4; f++){
            int row = 16*f + r;
            int c0 = (q ^ (r & 7)) * 8;
            int c1 = ((4 + q) ^ (r & 7)) * 8;
            bf16x8 bh0 = *(bf16x8*)&Bh_lds[row*64 + c0];
            bf16x8 bh1 = *(bf16x8*)&Bh_lds[row*64 + c1];
            bf16x8 bl0 = *(bf16x8*)&Bl_lds[row*64 + c0];
            bf16x8 bl1 = *(bf16x8*)&Bl_lds[row*64 + c1];
            #pragma unroll
            for (int g = 0; g < 2; g++){
                e[g][f] = mfma_bf16(Ah[g][0], bh0, e[g][f]);
                e[g][f] = mfma_bf16(Ah[g][0], bl0, e[g][f]);
                e[g][f] = mfma_bf16(Al[g][0], bh0, e[g][f]);
                e[g][f] = mfma_bf16(Ah[g][1], bh1, e[g][f]);
                e[g][f] = mfma_bf16(Ah[g][1], bl1, e[g][f]);
                e[g][f] = mfma_bf16(Al[g][1], bh1, e[g][f]);
            }
        }
        #pragma unroll
        for (int g = 0; g < 2; g++)
            #pragma unroll
            for (int i = 0; i < 4; i++){
                rs[g][i] += __expf(e[g][0][i] - sh[g][i]) + __expf(e[g][1][i] - sh[g][i])
                          + __expf(e[g][2][i] - sh[g][i]) + __expf(e[g][3][i] - sh[g][i]);
            }
        __syncthreads();
    }
    #pragma unroll
    for (int g = 0; g < 2; g++)
        #pragma unroll
        for (int i = 0; i < 4; i++){
            #pragma unroll
            for (int o = 1; o < 16; o <<= 1) rs[g][i] += __shfl_xor(rs[g][i], o);
        }
    if (r == 0){
        #pragma unroll
        for (int g = 0; g < 2; g++){
            float4 v; v.x = rs[g][0]; v.y = rs[g][1]; v.z = rs[g][2]; v.w = rs[g][3];
            *(float4*)&rsum_part[((size_t)ms*B_ + b)*N_ + n0 + 32*w + 16*g + 4*q] = v;
        }
    }
}

// shift2[b,n] = nrm*M + log(sum of 4 partials)
__global__ __launch_bounds__(256) void shiftfin_kernel(
    const float* __restrict__ rsum_part, const float* __restrict__ nrm,
    const float* __restrict__ Mv, float* __restrict__ shift2)
{
    int gi = blockIdx.x * 256 + threadIdx.x;   // over B*N
    int b = gi >> 12;
    float s = rsum_part[gi] + rsum_part[(size_t)B_*N_ + gi]
            + rsum_part[(size_t)2*B_*N_ + gi] + rsum_part[(size_t)3*B_*N_ + gi];
    shift2[gi] = nrm[gi]*Mv[b] + __logf(s);
}

// ---------------------------------------------------------------------------
// Pass 2: fused attention+PV, software-pipelined (P~ LDS double-buffer,
// one barrier per n-tile, prefetched A/xv frags).
__global__ __launch_bounds__(256, 2) void pv_kernel(
    const unsigned short* __restrict__ qh, const unsigned short* __restrict__ ql,
    const unsigned short* __restrict__ xvb, const float* __restrict__ shift2,
    const float* __restrict__ x, unsigned short* __restrict__ uT)
{
    __shared__ unsigned short Pt[2][64*72];   // P~ tile [m][n], stride 72
    __shared__ float red[4][64];
    __shared__ float csinv[64];
    int b = blockIdx.x, m0 = blockIdx.y * 64;
    int tid = threadIdx.x, w = tid >> 6, lane = tid & 63, q = lane >> 4, r = lane & 15;
    const unsigned short* qb = qh + (size_t)b*N_*D_;
    const unsigned short* lb = ql + (size_t)b*N_*D_;
    bf16x8 Bh[4][2], Bl[4][2];
    #pragma unroll
    for (int f = 0; f < 4; f++){
        const unsigned short* bp  = qb + (size_t)(m0 + 16*f + r)*D_ + 8*q;
        const unsigned short* blp = lb + (size_t)(m0 + 16*f + r)*D_ + 8*q;
        Bh[f][0] = ldf(bp);  Bh[f][1] = ldf(bp+32);
        Bl[f][0] = ldf(blp); Bl[f][1] = ldf(blp+32);
    }
    const unsigned short* xvbase = xvb + (size_t)b*C_*N_;
    f32x4 z = {0.f,0.f,0.f,0.f};
    f32x4 accv[4][4];
    #pragma unroll
    for (int cf = 0; cf < 4; cf++)
        #pragma unroll
        for (int fm = 0; fm < 4; fm++) accv[cf][fm] = z;
    float cs[4] = {0.f,0.f,0.f,0.f};

    const unsigned short* ap0  = qb + (size_t)(16*w + r)*D_ + 8*q;
    const unsigned short* alp0 = lb + (size_t)(16*w + r)*D_ + 8*q;
    bf16x8 Ah0 = ldf(ap0), Ah1 = ldf(ap0+32), Al0 = ldf(alp0), Al1 = ldf(alp0+32);
    int buf = 0;

    for (int ns = 0; ns < N_; ns += 64){
        bf16x8 xvf[2][4];
        #pragma unroll
        for (int kc = 0; kc < 2; kc++)
            #pragma unroll
            for (int cf = 0; cf < 4; cf++)
                xvf[kc][cf] = ldf(xvbase + (size_t)(64*w + 16*cf + r)*N_ + ns + kc*32 + 8*q);
        f32x4 e[4] = {z,z,z,z};
        #pragma unroll
        for (int f = 0; f < 4; f++){
            e[f] = mfma_bf16(Ah0, Bh[f][0], e[f]);
            e[f] = mfma_bf16(Ah0, Bl[f][0], e[f]);
            e[f] = mfma_bf16(Al0, Bh[f][0], e[f]);
            e[f] = mfma_bf16(Ah1, Bh[f][1], e[f]);
            e[f] = mfma_bf16(Ah1, Bl[f][1], e[f]);
            e[f] = mfma_bf16(Al1, Bh[f][1], e[f]);
        }
        if (ns + 64 < N_){
            const unsigned short* ap  = qb + (size_t)(ns + 64 + 16*w + r)*D_ + 8*q;
            const unsigned short* alp = lb + (size_t)(ns + 64 + 16*w + r)*D_ + 8*q;
            Ah0 = ldf(ap); Ah1 = ldf(ap+32); Al0 = ldf(alp); Al1 = ldf(alp+32);
        }
        float4 s2 = *(const float4*)&shift2[(size_t)b*N_ + ns + 16*w + 4*q];
        float sh[4] = {s2.x, s2.y, s2.z, s2.w};
        #pragma unroll
        for (int f = 0; f < 4; f++){
            float p0 = __expf(e[f][0] - sh[0]);
            float p1 = __expf(e[f][1] - sh[1]);
            float p2 = __expf(e[f][2] - sh[2]);
            float p3 = __expf(e[f][3] - sh[3]);
            cs[f] += p0 + p1 + p2 + p3;
            ushort4 pv4;
            pv4.x = f2bf(p0); pv4.y = f2bf(p1); pv4.z = f2bf(p2); pv4.w = f2bf(p3);
            *(ushort4*)&Pt[buf][(16*f + r)*72 + 16*w + 4*q] = pv4;
        }
        __syncthreads();
        #pragma unroll
        for (int kc = 0; kc < 2; kc++){
            bf16x8 bfr[4];
            #pragma unroll
            for (int fm = 0; fm < 4; fm++)
                bfr[fm] = *(bf16x8*)&Pt[buf][(16*fm + r)*72 + kc*32 + 8*q];
            #pragma unroll
            for (int cf = 0; cf < 4; cf++)
                #pragma unroll
                for (int fm = 0; fm < 4; fm++)
                    accv[cf][fm] = mfma_bf16(xvf[kc][cf], bfr[fm], accv[cf][fm]);
        }
        buf ^= 1;
    }
    #pragma unroll
    for (int f = 0; f < 4; f++){
        float v = cs[f];
        v += __shfl_xor(v, 16);
        v += __shfl_xor(v, 32);
        if (q == 0) red[w][16*f + r] = v;
    }
    __syncthreads();
    if (tid < 64)
        csinv[tid] = 1.0f / (1e-9f + red[0][tid] + red[1][tid] + red[2][tid] + red[3][tid]);
    __syncthreads();
    #pragma unroll
    for (int fm = 0; fm < 4; fm++){
        int m = m0 + 16*fm + r;
        float inv = csinv[16*fm + r];
        #pragma unroll
        for (int cf = 0; cf < 4; cf++){
            int c0r = 64*w + 16*cf + 4*q;
            float u0 = x[(size_t)(b*C_ + c0r+0)*N_ + m] - accv[cf][fm][0]*inv;
            float u1 = x[(size_t)(b*C_ + c0r+1)*N_ + m] - accv[cf][fm][1]*inv;
            float u2 = x[(size_t)(b*C_ + c0r+2)*N_ + m] - accv[cf][fm][2]*inv;
            float u3 = x[(size_t)(b*C_ + c0r+3)*N_ + m] - accv[cf][fm][3]*inv;
            ushort4 uv;
            uv.x = f2bf(u0); uv.y = f2bf(u1); uv.z = f2bf(u2); uv.w = f2bf(u3);
            *(ushort4*)&uT[((size_t)b*N_ + m)*C_ + c0r] = uv;
        }
    }
}

// ---------------------------------------------------------------------------
__global__ __launch_bounds__(256) void t_stats_kernel(
    const unsigned short* __restrict__ uT, const unsigned short* __restrict__ Wtb,
    float* __restrict__ bnsum, float* __restrict__ bnsq)
{
    int b = blockIdx.z, n0 = blockIdx.x * 64, d0 = blockIdx.y * 64;
    int tid = threadIdx.x, w = tid >> 6, lane = tid & 63, q = lane >> 4, r = lane & 15;
    f32x4 z = {0.f,0.f,0.f,0.f};
    f32x4 acc[4] = {z,z,z,z};
    const unsigned short* A = Wtb + (size_t)(d0 + 16*w + r)*C_;
    const unsigned short* Bb = uT + ((size_t)(b*N_ + n0 + r))*C_;
    for (int k0 = 0; k0 < C_; k0 += 32){
        bf16x8 a = ldf(A + k0 + 8*q);
        #pragma unroll
        for (int f = 0; f < 4; f++){
            bf16x8 bb = ldf(Bb + (size_t)(16*f)*C_ + k0 + 8*q);
            acc[f] = mfma_bf16(a, bb, acc[f]);
        }
    }
    #pragma unroll
    for (int i = 0; i < 4; i++){
        float s = 0.f, s2 = 0.f;
        #pragma unroll
        for (int f = 0; f < 4; f++){ float v = acc[f][i]; s += v; s2 += v*v; }
        #pragma unroll
        for (int o = 1; o < 16; o <<= 1){ s += __shfl_xor(s, o); s2 += __shfl_xor(s2, o); }
        if (r == 0){
            int d = d0 + 16*w + 4*q + i;
            atomicAdd(&bnsum[d], s);
            atomicAdd(&bnsq[d], s2);
        }
    }
}

__global__ __launch_bounds__(256) void bn_final_kernel(
    const float* __restrict__ bnsum, const float* __restrict__ bnsq,
    const float* __restrict__ gamma, const float* __restrict__ beta,
    float* __restrict__ scale, float* __restrict__ shift)
{
    int d = threadIdx.x;
    const float inv = 1.0f / (B_ * N_);
    float m = bnsum[d] * inv;
    float v = bnsq[d] * inv - m*m;
    float rs = rsqrtf(v + 1e-5f);
    float sc = gamma[d] * rs;
    scale[d] = sc;
    shift[d] = beta[d] - m*sc;
}

__global__ __launch_bounds__(256) void final_kernel(
    const unsigned short* __restrict__ uT, const unsigned short* __restrict__ Wtb,
    const float* __restrict__ scale, const float* __restrict__ shift,
    const float* __restrict__ x, float* __restrict__ out)
{
    int b = blockIdx.z, n0 = blockIdx.x * 64, d0 = blockIdx.y * 64;
    int tid = threadIdx.x, w = tid >> 6, lane = tid & 63, q = lane >> 4, r = lane & 15;
    f32x4 z = {0.f,0.f,0.f,0.f};
    f32x4 acc[4] = {z,z,z,z};
    const unsigned short* A = Wtb + (size_t)(d0 + 16*w + r)*C_;
    const unsigned short* Bb = uT + ((size_t)(b*N_ + n0 + r))*C_;
    for (int k0 = 0; k0 < C_; k0 += 32){
        bf16x8 a = ldf(A + k0 + 8*q);
        #pragma unroll
        for (int f = 0; f < 4; f++){
            bf16x8 bb = ldf(Bb + (size_t)(16*f)*C_ + k0 + 8*q);
            acc[f] = mfma_bf16(a, bb, acc[f]);
        }
    }
    #pragma unroll
    for (int f = 0; f < 4; f++){
        int n = n0 + 16*f + r;
        #pragma unroll
        for (int i = 0; i < 4; i++){
            int d = d0 + 16*w + 4*q + i;
            float tv = acc[f][i]*scale[d] + shift[d];
            tv = fmaxf(tv, 0.0f);
            size_t o = ((size_t)(b*C_ + d))*N_ + n;
            out[o] = x[o] + tv;
        }
    }
}

// ---------------------------------------------------------------------------
extern "C" void kernel_launch(void* const* d_in, const int* in_sizes, int n_in,
                              void* d_out, int out_size, void* d_ws, size_t ws_size,
                              hipStream_t stream)
{
    const float* x     = (const float*)d_in[0];
    const float* Wqk   = (const float*)d_in[1];
    const float* Wv    = (const float*)d_in[2];
    const float* bv    = (const float*)d_in[3];
    const float* Wt    = (const float*)d_in[4];
    // d_in[5] = bt : cancels exactly through training-mode BatchNorm
    const float* gamma = (const float*)d_in[6];
    const float* beta  = (const float*)d_in[7];
    float* out = (float*)d_out;

    char* ws = (char*)d_ws;
    size_t off = 0;
    auto alloc = [&](size_t bytes) -> void* {
        void* p = ws + off;
        off += (bytes + 255) & ~(size_t)255;
        return p;
    };
    unsigned short* xhT    = (unsigned short*)alloc((size_t)B_*N_*C_*2);
    unsigned short* xlT    = (unsigned short*)alloc((size_t)B_*N_*C_*2);
    unsigned short* Wqk_hi = (unsigned short*)alloc((size_t)D_*C_*2);
    unsigned short* Wqk_lo = (unsigned short*)alloc((size_t)D_*C_*2);
    unsigned short* Wv_b   = (unsigned short*)alloc((size_t)C_*C_*2);
    unsigned short* Wt_b   = (unsigned short*)alloc((size_t)C_*C_*2);
    unsigned short* qh     = (unsigned short*)alloc((size_t)B_*N_*D_*2);
    unsigned short* ql     = (unsigned short*)alloc((size_t)B_*N_*D_*2);
    unsigned short* xvb    = (unsigned short*)alloc((size_t)B_*C_*N_*2);
    unsigned short* uT     = (unsigned short*)alloc((size_t)B_*N_*C_*2);
    float*          nrm    = (float*)alloc((size_t)B_*N_*4);
    float*          Mv     = (float*)alloc(B_*4);
    float*          rsum_part = (float*)alloc((size_t)4*B_*N_*4);
    float*          shift2 = (float*)alloc((size_t)B_*N_*4);
    float*          bnsum  = (float*)alloc(256*4);
    float*          bnsq   = (float*)alloc(256*4);
    float*          scale  = (float*)alloc(256*4);
    float*          shiftb = (float*)alloc(256*4);

    convert_x_kernel<<<dim3(N_/64, C_/64, B_), 256, 0, stream>>>(x, xhT, xlT);
    convert_w_kernel<<<(D_*C_ + 2*C_*C_ + 255)/256, 256, 0, stream>>>(
        Wqk, Wv, Wt, Wqk_hi, Wqk_lo, Wv_b, Wt_b);
    proj_qk_kernel<<<dim3(N_/64, 1, B_), 256, 0, stream>>>(xhT, xlT, Wqk_hi, Wqk_lo, qh, ql);
    qnorm_kernel<<<(B_*N_)/4, 256, 0, stream>>>(qh, ql, nrm);
    qmax_kernel<<<B_, 256, 0, stream>>>(nrm, Mv);
    proj_v_kernel<<<dim3(N_/64, C_/64, B_), 256, 0, stream>>>(xhT, Wv_b, bv, xvb);

    rsum_kernel<<<dim3(B_, N_/128, 4), 256, 0, stream>>>(qh, ql, nrm, Mv, rsum_part);
    shiftfin_kernel<<<(B_*N_)/256, 256, 0, stream>>>(rsum_part, nrm, Mv, shift2);
    pv_kernel<<<dim3(B_, N_/64), 256, 0, stream>>>(qh, ql, xvb, shift2, x, uT);

    hipMemsetAsync(bnsum, 0, 256*4, stream);
    hipMemsetAsync(bnsq, 0, 256*4, stream);
    t_stats_kernel<<<dim3(N_/64, C_/64, B_), 256, 0, stream>>>(uT, Wt_b, bnsum, bnsq);
    bn_final_kernel<<<1, 256, 0, stream>>>(bnsum, bnsq, gamma, beta, scale, shiftb);
    final_kernel<<<dim3(N_/64, C_/64, B_), 256, 0, stream>>>(uT, Wt_b, scale, shiftb, x, out);
}